// Round 13
// baseline (41915.231 us; speedup 1.0000x reference)
//
#include <hip/hip_runtime.h>
#include <hip/hip_bf16.h>
#include <stdint.h>

// ============================================================================
// 2-layer GRU — ROUND 13: RELAXED stamps (no release/acquire in hot path).
//   B=64, S=1024, I=256, H=1024, O=256, L=2
// R8-R12 post-mortem: all rounds stuck at ~20us/hop share agent-scope
// release/acquire ops -> compiler emits buffer_wbl2 / buffer_inv (L2
// cache-maintenance sweeps), ~25 per XCD per step, serializing at L2.
// Fix: ordering via {relaxed sc1 data stores -> syncthreads vmcnt drain
// (data ACKed at LLC) -> RELAXED sc1 stamp store}; consumers poll and read
// via relaxed sc1 loads (no L1/L2 involvement, no fences). Single change
// vs R10: stamp RELEASE -> RELAXED (R12's cached-read experiment reverted).
// Pipeline/thresholds identical to R10:
//   zr0(t): g0 off1        g0(t): zr0 off2, zr1 off0, g1 off0
//   zr1(t): g0 off2, g1 off1    g1(t): zr1 off2, g0 off2, y off0
//   y(t):   g1 off2        hs:    g0,g1 >= Sc+1
// ============================================================================

#define NWG 200
#define TPB 256

typedef unsigned long long u64;
typedef __attribute__((ext_vector_type(8))) short bfrag;
typedef __attribute__((ext_vector_type(4))) float f32x4;

constexpr int Bc = 64, Sc = 1024, Ic = 256, Hc = 1024, Oc = 256;

struct Args {
  const float *x, *h0in;
  const float *W1[7], *W2[7], *bias[7];
  unsigned short *h0[2], *h1[2], *z0[2], *rh0[2], *z1[2], *rh1[2];
  unsigned *sl;       // 200 stamp slots, 128B apart
  float *y, *hs;
};

__device__ __forceinline__ u64 ald64(const void *p) {
  return __hip_atomic_load((const u64 *)p, __ATOMIC_RELAXED, __HIP_MEMORY_SCOPE_AGENT);
}
__device__ __forceinline__ unsigned ald32(const void *p) {
  return __hip_atomic_load((const unsigned *)p, __ATOMIC_RELAXED, __HIP_MEMORY_SCOPE_AGENT);
}
__device__ __forceinline__ void ast32(void *p, unsigned v) {
  __hip_atomic_store((unsigned *)p, v, __ATOMIC_RELAXED, __HIP_MEMORY_SCOPE_AGENT);
}
__device__ __forceinline__ unsigned short f2b(float x) {
  __hip_bfloat16 b = __float2bfloat16(x);
  return __builtin_bit_cast(unsigned short, b);
}
__device__ __forceinline__ float b2f(unsigned short u) {
  return __uint_as_float(((unsigned)u) << 16);
}

// ---------------- dataflow sync (all relaxed, no cache maintenance) ---------
__device__ void waitslots(const unsigned *sl, int pslot, int pthr) {
  __shared__ int notdone;
  while (true) {
    int bad = 0;
    if (pslot >= 0)
      bad = ((int)ald32(sl + (size_t)pslot * 32) < pthr);
    if (threadIdx.x == 0) notdone = 0;
    __syncthreads();
    if (bad) notdone = 1;
    __syncthreads();
    if (!notdone) break;
    __builtin_amdgcn_s_sleep(2);
  }
}

// syncthreads drains vmcnt: all of this WG's sc1 stores are ACKed at the LLC
// before the (relaxed) stamp store issues -> observers that see the stamp
// see the data. No release -> no buffer_wbl2.
__device__ void stamp(unsigned *sl, int wg, unsigned v) {
  __syncthreads();
  if (threadIdx.x == 0)
    __hip_atomic_store(sl + (size_t)wg * 32, v, __ATOMIC_RELAXED, __HIP_MEMORY_SCOPE_AGENT);
}

// ---------------- MFMA segments (sc1 8B loads, 16-deep batches) -------------
__device__ __forceinline__ void ldb(u64 *dst, const u64 *ap, int ks) {
#pragma unroll
  for (int q = 0; q < 8; ++q) {
    dst[2 * q]     = ald64(ap + (size_t)(ks + q) * 8);
    dst[2 * q + 1] = ald64(ap + (size_t)(ks + q) * 8 + 1);
  }
}
__device__ __forceinline__ void useb(f32x4 *acc, const u64 *src, const short *wl,
                                     int nkoff, int ks, int lane) {
#pragma unroll
  for (int q = 0; q < 8; ++q) {
    union { u64 u[2]; bfrag v; } cc;
    cc.u[0] = src[2 * q]; cc.u[1] = src[2 * q + 1];
    const short *wp = wl + (((size_t)(nkoff + ks + q) * 2) * 64 + lane) * 8;
    acc[0] = __builtin_amdgcn_mfma_f32_16x16x32_bf16(cc.v, *(const bfrag *)wp, acc[0], 0, 0, 0);
    acc[1] = __builtin_amdgcn_mfma_f32_16x16x32_bf16(cc.v, *(const bfrag *)(wp + 512), acc[1], 0, 0, 0);
  }
}
__device__ void seg_h(f32x4 *acc, const unsigned short *hb, const short *wl,
                      int nkoff, int lane, int rbase) {
  const u64 *ap = (const u64 *)(hb + (size_t)(rbase + (lane & 15)) * Hc) + (lane >> 4) * 2;
  u64 A[16], B[16];
  ldb(A, ap, 0);
  ldb(B, ap, 8);
  useb(acc, A, wl, nkoff, 0, lane);
  ldb(A, ap, 16);
  useb(acc, B, wl, nkoff, 8, lane);
  ldb(B, ap, 24);
  useb(acc, A, wl, nkoff, 16, lane);
  useb(acc, B, wl, nkoff, 24, lane);
}
// x is a read-only input -> plain cached loads are always fresh.
__device__ void seg_x(f32x4 *acc, const float *xt, const short *wl, int lane, int rbase) {
  const float4 *xp = (const float4 *)(xt + (size_t)(rbase + (lane & 15)) * Sc * Ic) + (lane >> 4) * 2;
  float4 xv[16];
#pragma unroll
  for (int q = 0; q < 8; ++q) {
    xv[2 * q]     = xp[(size_t)q * 8];
    xv[2 * q + 1] = xp[(size_t)q * 8 + 1];
  }
#pragma unroll
  for (int q = 0; q < 8; ++q) {
    bfrag av;
    const float *f0 = (const float *)&xv[2 * q];
    const float *f1 = (const float *)&xv[2 * q + 1];
#pragma unroll
    for (int e = 0; e < 4; ++e) {
      av[e]     = (short)f2b(f0[e]);
      av[4 + e] = (short)f2b(f1[e]);
    }
    const short *wp = wl + (((size_t)q * 2) * 64 + lane) * 8;
    acc[0] = __builtin_amdgcn_mfma_f32_16x16x32_bf16(av, *(const bfrag *)wp, acc[0], 0, 0, 0);
    acc[1] = __builtin_amdgcn_mfma_f32_16x16x32_bf16(av, *(const bfrag *)(wp + 512), acc[1], 0, 0, 0);
  }
}

// ---------------- epilogues (sc1 reads, sc1 writes) --------------------------
__device__ void store_sig(unsigned short *out, f32x4 *acc, int c0, int lane, int rbase) {
#pragma unroll
  for (int nt = 0; nt < 2; ++nt) {
    int col = c0 + nt * 16 + (lane & 15);
#pragma unroll
    for (int j = 0; j < 4; ++j) {
      float v = 1.f / (1.f + expf(-acc[nt][j]));
      float vo = __shfl_xor(v, 1);
      if (!(lane & 1)) {
        int row = rbase + (lane >> 4) * 4 + j;
        ast32((unsigned *)out + (((size_t)row * Hc + col) >> 1),
              (unsigned)f2b(v) | ((unsigned)f2b(vo) << 16));
      }
    }
  }
}
__device__ void store_rh(unsigned short *out, const unsigned short *hb, f32x4 *acc,
                         int c0, int lane, int rbase) {
  unsigned hw[8];
#pragma unroll
  for (int nt = 0; nt < 2; ++nt)
#pragma unroll
    for (int j = 0; j < 4; ++j)
      if (!(lane & 1)) {
        int col = c0 + nt * 16 + (lane & 15);
        int row = rbase + (lane >> 4) * 4 + j;
        hw[nt * 4 + j] = ald32((const unsigned *)hb + (((size_t)row * Hc + col) >> 1));
      }
#pragma unroll
  for (int nt = 0; nt < 2; ++nt) {
    int col = c0 + nt * 16 + (lane & 15);
#pragma unroll
    for (int j = 0; j < 4; ++j) {
      float v = 1.f / (1.f + expf(-acc[nt][j]));
      float vo = __shfl_xor(v, 1);
      if (!(lane & 1)) {
        unsigned w = hw[nt * 4 + j];
        int row = rbase + (lane >> 4) * 4 + j;
        unsigned pk = (unsigned)f2b(v * b2f((unsigned short)(w & 0xffff)))
                    | ((unsigned)f2b(vo * b2f((unsigned short)(w >> 16))) << 16);
        ast32((unsigned *)out + (((size_t)row * Hc + col) >> 1), pk);
      }
    }
  }
}
__device__ void store_gupd(unsigned short *hnew, const unsigned short *hold,
                           const unsigned short *zb, f32x4 *acc, int c0, int lane, int rbase) {
  unsigned zw[8], hw[8];
#pragma unroll
  for (int nt = 0; nt < 2; ++nt)
#pragma unroll
    for (int j = 0; j < 4; ++j)
      if (!(lane & 1)) {
        int col = c0 + nt * 16 + (lane & 15);
        size_t iw = ((size_t)(rbase + (lane >> 4) * 4 + j) * Hc + col) >> 1;
        zw[nt * 4 + j] = ald32((const unsigned *)zb + iw);
        hw[nt * 4 + j] = ald32((const unsigned *)hold + iw);
      }
#pragma unroll
  for (int nt = 0; nt < 2; ++nt) {
    int col = c0 + nt * 16 + (lane & 15);
#pragma unroll
    for (int j = 0; j < 4; ++j) {
      float g = tanhf(acc[nt][j]);
      float go = __shfl_xor(g, 1);
      if (!(lane & 1)) {
        unsigned wz = zw[nt * 4 + j], wh = hw[nt * 4 + j];
        float zl = b2f((unsigned short)(wz & 0xffff)), zh = b2f((unsigned short)(wz >> 16));
        float hl = b2f((unsigned short)(wh & 0xffff)), hh = b2f((unsigned short)(wh >> 16));
        float hn0 = zl * hl + (1.f - zl) * g;
        float hn1 = zh * hh + (1.f - zh) * go;
        size_t iw = ((size_t)(rbase + (lane >> 4) * 4 + j) * Hc + col) >> 1;
        ast32((unsigned *)hnew + iw, (unsigned)f2b(hn0) | ((unsigned)f2b(hn1) << 16));
      }
    }
  }
}

// ---------------- weight packing --------------------------------------------
__device__ void pack_weights(short *wl, const float *W1, int K1, int ld1,
                             const float *W2, int K2, int ld2, int c0) {
  int NK = (K1 + K2) / 32;
  for (int slot = threadIdx.x; slot < NK * 128; slot += TPB) {
    int ks = slot >> 7, rem = slot & 127, nt = rem >> 6, ln = rem & 63;
    int c = c0 + nt * 16 + (ln & 15);
    int k0 = ks * 32 + (ln >> 4) * 8;
    short *dst = wl + (((size_t)ks * 2 + nt) * 64 + ln) * 8;
#pragma unroll
    for (int j = 0; j < 8; ++j) {
      int k = k0 + j;
      float w = (k < K1) ? W1[(size_t)k * ld1 + c] : W2[(size_t)(k - K1) * ld2 + c];
      dst[j] = (short)f2b(w);
    }
  }
}

// ---------------- main ------------------------------------------------------
__global__ void __launch_bounds__(TPB) gru_df(Args a) {
  extern __shared__ short wl[];
  const int wg = blockIdx.x, tid = threadIdx.x;
  const int lane = tid & 63, wid = tid >> 6, rbase = wid * 16;
  const int gate = (wg < 32) ? 0 : (wg < 64) ? 1 : (wg < 96) ? 2 :
                   (wg < 128) ? 3 : (wg < 160) ? 4 : (wg < 192) ? 5 : 6;
  const int c0 = (gate == 6) ? (wg - 192) * 32 : (wg - gate * 32) * 32;
  static const int K1tab[7] = {256, 256, 256, 1024, 1024, 1024, 1024};
  static const int K2tab[7] = {1024, 1024, 1024, 1024, 1024, 1024, 0};
  const int ld1 = (gate == 6) ? Oc : Hc;

  pack_weights(wl, a.W1[gate], K1tab[gate], ld1, a.W2[gate], K2tab[gate], Hc, c0);

  // per-thread poll assignment: (slot, threshold offset); thr = t + off
  int pslot = -1, poff = 0;
  if (gate <= 1) {
    if (tid < 32) { pslot = 64 + tid; poff = 1; }                 // g0
  } else if (gate == 2) {
    if (tid < 64)       { pslot = tid;              poff = 2; }   // zr0
    else if (tid < 128) { pslot = 96 + (tid - 64);  poff = 0; }   // zr1 (WAR)
    else if (tid < 160) { pslot = 160 + (tid - 128); poff = 0; }  // g1 (WAR)
  } else if (gate <= 4) {
    if (tid < 32)      { pslot = 64 + tid;          poff = 2; }   // g0
    else if (tid < 64) { pslot = 160 + (tid - 32);  poff = 1; }   // g1
  } else if (gate == 5) {
    if (tid < 64)       { pslot = 96 + tid;         poff = 2; }   // zr1
    else if (tid < 96)  { pslot = 64 + (tid - 64);  poff = 2; }   // g0
    else if (tid < 104) { pslot = 192 + (tid - 96); poff = 0; }   // y (WAR)
  } else {
    if (tid < 32) { pslot = 160 + tid; poff = 2; }                // g1
  }

  // init h(-1) into buf1 (h0[1], h1[1]), packed bf16 via sc1 stores
  for (int u = wg * TPB + tid; u < Bc * Hc / 2; u += NWG * TPB) {
    int b = u >> 9, hp = (u & 511) * 2;
    const float *s0 = a.h0in + (size_t)(b * 2) * Hc + hp;
    const float *s1 = a.h0in + (size_t)(b * 2 + 1) * Hc + hp;
    ast32((unsigned *)a.h0[1] + u, (unsigned)f2b(s0[0]) | ((unsigned)f2b(s0[1]) << 16));
    ast32((unsigned *)a.h1[1] + u, (unsigned)f2b(s1[0]) | ((unsigned)f2b(s1[1]) << 16));
  }
  stamp(a.sl, wg, 1);
  waitslots(a.sl, (tid < NWG) ? tid : -1, 1);

  const float *bias = a.bias[gate];

  if (gate <= 1) {                                   // ---- zr0
    for (int t = 0; t < Sc; ++t) {
      waitslots(a.sl, pslot, (pslot >= 0) ? t + poff : 0);
      const unsigned short *h0c = a.h0[(t + 1) & 1];             // h0(t-1)
      float b0 = bias[c0 + (lane & 15)], b1 = bias[c0 + 16 + (lane & 15)];
      f32x4 acc[2] = {{b0, b0, b0, b0}, {b1, b1, b1, b1}};
      seg_x(acc, a.x + (size_t)t * Ic, wl, lane, rbase);
      seg_h(acc, h0c, wl, 8, lane, rbase);
      if (gate == 0) store_sig(a.z0[t & 1], acc, c0, lane, rbase);
      else           store_rh(a.rh0[t & 1], h0c, acc, c0, lane, rbase);
      stamp(a.sl, wg, t + 2);
    }
  } else if (gate == 2) {                            // ---- g0
    for (int t = 0; t < Sc; ++t) {
      waitslots(a.sl, pslot, (pslot >= 0) ? t + poff : 0);
      const unsigned short *h0c = a.h0[(t + 1) & 1];
      unsigned short *h0n = a.h0[t & 1];                          // h0(t)
      float b0 = bias[c0 + (lane & 15)], b1 = bias[c0 + 16 + (lane & 15)];
      f32x4 acc[2] = {{b0, b0, b0, b0}, {b1, b1, b1, b1}};
      seg_x(acc, a.x + (size_t)t * Ic, wl, lane, rbase);
      seg_h(acc, a.rh0[t & 1], wl, 8, lane, rbase);
      store_gupd(h0n, h0c, a.z0[t & 1], acc, c0, lane, rbase);
      stamp(a.sl, wg, t + 2);
    }
    // hs epilogue: final h0(1023), h1(1023) in buf1
    {
      int eslot = -1;
      if (tid < 32) eslot = 64 + tid;
      else if (tid < 64) eslot = 160 + (tid - 32);
      waitslots(a.sl, eslot, Sc + 1);
    }
    for (int k = (wg - 64) * TPB + tid; k < Bc * 2 * Hc; k += 32 * TPB) {
      int b = k >> 11, l = (k >> 10) & 1, h = k & 1023;
      const unsigned short *src = l ? a.h1[1] : a.h0[1];
      size_t idx = (size_t)b * Hc + h;
      unsigned wv = ald32((const unsigned *)src + idx / 2);
      a.hs[k] = b2f((unsigned short)((h & 1) ? (wv >> 16) : (wv & 0xffff)));
    }
  } else if (gate <= 4) {                            // ---- zr1
    for (int t = 0; t < Sc; ++t) {
      waitslots(a.sl, pslot, (pslot >= 0) ? t + poff : 0);
      const unsigned short *h0n = a.h0[t & 1];                    // h0(t)
      const unsigned short *h1c = a.h1[(t + 1) & 1];              // h1(t-1)
      float b0 = bias[c0 + (lane & 15)], b1 = bias[c0 + 16 + (lane & 15)];
      f32x4 acc[2] = {{b0, b0, b0, b0}, {b1, b1, b1, b1}};
      seg_h(acc, h0n, wl, 0, lane, rbase);
      seg_h(acc, h1c, wl, 32, lane, rbase);
      if (gate == 3) store_sig(a.z1[t & 1], acc, c0, lane, rbase);
      else           store_rh(a.rh1[t & 1], h1c, acc, c0, lane, rbase);
      stamp(a.sl, wg, t + 2);
    }
  } else if (gate == 5) {                            // ---- g1
    for (int t = 0; t < Sc; ++t) {
      waitslots(a.sl, pslot, (pslot >= 0) ? t + poff : 0);
      const unsigned short *h0n = a.h0[t & 1];
      const unsigned short *h1c = a.h1[(t + 1) & 1];
      unsigned short *h1n = a.h1[t & 1];                          // h1(t)
      float b0 = bias[c0 + (lane & 15)], b1 = bias[c0 + 16 + (lane & 15)];
      f32x4 acc[2] = {{b0, b0, b0, b0}, {b1, b1, b1, b1}};
      seg_h(acc, h0n, wl, 0, lane, rbase);
      seg_h(acc, a.rh1[t & 1], wl, 32, lane, rbase);
      store_gupd(h1n, h1c, a.z1[t & 1], acc, c0, lane, rbase);
      stamp(a.sl, wg, t + 2);
    }
  } else {                                           // ---- y
    for (int t = 0; t < Sc; ++t) {
      waitslots(a.sl, pslot, (pslot >= 0) ? t + poff : 0);
      const unsigned short *h1t = a.h1[t & 1];                    // h1(t)
      float b0 = bias[c0 + (lane & 15)], b1 = bias[c0 + 16 + (lane & 15)];
      f32x4 acc[2] = {{b0, b0, b0, b0}, {b1, b1, b1, b1}};
      seg_h(acc, h1t, wl, 0, lane, rbase);
#pragma unroll
      for (int nt = 0; nt < 2; ++nt) {
        int col = c0 + nt * 16 + (lane & 15);
#pragma unroll
        for (int j = 0; j < 4; ++j) {
          int row = rbase + (lane >> 4) * 4 + j;
          a.y[((size_t)row * Sc + t) * Oc + col] = acc[nt][j];
        }
      }
      stamp(a.sl, wg, t + 2);
    }
  }
}

extern "C" void kernel_launch(void *const *d_in, const int *in_sizes, int n_in,
                              void *d_out, int out_size, void *d_ws, size_t ws_size,
                              hipStream_t stream) {
  (void)in_sizes; (void)n_in; (void)out_size; (void)ws_size;
  Args a;
  a.x    = (const float *)d_in[0];
  a.h0in = (const float *)d_in[1];
  a.W1[0] = (const float *)d_in[2];  a.W2[0] = (const float *)d_in[5];  a.bias[0] = (const float *)d_in[6];
  a.W1[1] = (const float *)d_in[3];  a.W2[1] = (const float *)d_in[7];  a.bias[1] = (const float *)d_in[8];
  a.W1[2] = (const float *)d_in[4];  a.W2[2] = (const float *)d_in[9];  a.bias[2] = (const float *)d_in[10];
  a.W1[3] = (const float *)d_in[11]; a.W2[3] = (const float *)d_in[14]; a.bias[3] = (const float *)d_in[15];
  a.W1[4] = (const float *)d_in[12]; a.W2[4] = (const float *)d_in[16]; a.bias[4] = (const float *)d_in[17];
  a.W1[5] = (const float *)d_in[13]; a.W2[5] = (const float *)d_in[18]; a.bias[5] = (const float *)d_in[19];
  a.W1[6] = (const float *)d_in[20]; a.W2[6] = nullptr;                 a.bias[6] = (const float *)d_in[21];

  char *w = (char *)d_ws;
  a.h0[0]  = (unsigned short *)(w + 0);
  a.h0[1]  = (unsigned short *)(w + 131072);
  a.h1[0]  = (unsigned short *)(w + 262144);
  a.h1[1]  = (unsigned short *)(w + 393216);
  a.z0[0]  = (unsigned short *)(w + 524288);
  a.z0[1]  = (unsigned short *)(w + 655360);
  a.rh0[0] = (unsigned short *)(w + 786432);
  a.rh0[1] = (unsigned short *)(w + 917504);
  a.z1[0]  = (unsigned short *)(w + 1048576);
  a.z1[1]  = (unsigned short *)(w + 1179648);
  a.rh1[0] = (unsigned short *)(w + 1310720);
  a.rh1[1] = (unsigned short *)(w + 1441792);
  a.sl     = (unsigned *)(w + 1572864);
  a.y   = (float *)d_out;
  a.hs  = a.y + (size_t)Bc * Sc * Oc;

  (void)hipMemsetAsync(a.sl, 0, 32768, stream);
  (void)hipFuncSetAttribute((const void *)gru_df,
                            hipFuncAttributeMaxDynamicSharedMemorySize, 131072);
  gru_df<<<NWG, TPB, 131072, stream>>>(a);
}

// Round 15
// 37765.591 us; speedup vs baseline: 1.1099x; 1.1099x over previous
//
#include <hip/hip_runtime.h>
#include <hip/hip_bf16.h>
#include <stdint.h>

// ============================================================================
// 2-layer GRU — ROUND 15: fragment-tiled state + R13's SAFE load path.
//   B=64, S=1024, I=256, H=1024, O=256, L=2
// R14 crash: inline-asm ld8 lacked early-clobber ("=&v") -> load results
// could overwrite later loads' address VGPRs -> wild address fault. This
// round keeps R14's TILED layout (tile[(k>>3)*64+row] = 16B fragment of
// (row, k..k+7)) but loads it with R13's proven __hip_atomic_load u64
// pairs: lanes 0-15 hit 16 consecutive tiles = 256B contiguous, so the
// wave's 64 lanes form 4x256B runs -> HW coalesces into 128B line
// requests (~16x fewer LLC transactions than R13's 2KB-strided reads).
// Everything else (sync, pipeline, values, rounding) identical to R13/R14.
//   zr0(t): g0 off1        g0(t): zr0 off2, zr1 off0, g1 off0
//   zr1(t): g0 off2, g1 off1    g1(t): zr1 off2, g0 off2, y off0
//   y(t):   g1 off2        hs:    g0,g1 >= Sc+1
// ============================================================================

#define NWG 200
#define TPB 256

typedef unsigned long long u64;
typedef __attribute__((ext_vector_type(8))) short bfrag;
typedef __attribute__((ext_vector_type(4))) float f32x4;

constexpr int Bc = 64, Sc = 1024, Ic = 256, Hc = 1024, Oc = 256;

struct Args {
  const float *x, *h0in;
  const float *W1[7], *W2[7], *bias[7];
  unsigned short *h0[2], *h1[2], *z0[2], *rh0[2], *z1[2], *rh1[2];
  unsigned *sl;       // 200 stamp slots, 128B apart
  float *y, *hs;
};

__device__ __forceinline__ u64 ald64(const void *p) {
  return __hip_atomic_load((const u64 *)p, __ATOMIC_RELAXED, __HIP_MEMORY_SCOPE_AGENT);
}
__device__ __forceinline__ unsigned ald32(const void *p) {
  return __hip_atomic_load((const unsigned *)p, __ATOMIC_RELAXED, __HIP_MEMORY_SCOPE_AGENT);
}
__device__ __forceinline__ void ast32(void *p, unsigned v) {
  __hip_atomic_store((unsigned *)p, v, __ATOMIC_RELAXED, __HIP_MEMORY_SCOPE_AGENT);
}
__device__ __forceinline__ unsigned short f2b(float x) {
  __hip_bfloat16 b = __float2bfloat16(x);
  return __builtin_bit_cast(unsigned short, b);
}
__device__ __forceinline__ float b2f(unsigned short u) {
  return __uint_as_float(((unsigned)u) << 16);
}
// tiled u32 index for (row, col): tile = (col>>3)*64+row, word = (col&7)>>1
__device__ __forceinline__ size_t tidx32(int row, int col) {
  return ((size_t)(col >> 3) * 64 + row) * 4 + ((col & 7) >> 1);
}

// ---------------- dataflow sync (relaxed, unchanged from R13) ----------------
__device__ void waitslots(const unsigned *sl, int pslot, int pthr) {
  __shared__ int notdone;
  while (true) {
    int bad = 0;
    if (pslot >= 0)
      bad = ((int)ald32(sl + (size_t)pslot * 32) < pthr);
    if (threadIdx.x == 0) notdone = 0;
    __syncthreads();
    if (bad) notdone = 1;
    __syncthreads();
    if (!notdone) break;
    __builtin_amdgcn_s_sleep(2);
  }
}
__device__ void stamp(unsigned *sl, int wg, unsigned v) {
  __syncthreads();   // vmcnt drain: all sc1 stores ACKed at LLC before stamp
  if (threadIdx.x == 0)
    __hip_atomic_store(sl + (size_t)wg * 32, v, __ATOMIC_RELAXED, __HIP_MEMORY_SCOPE_AGENT);
}

// ---------------- MFMA segments (tiled state, coalesced u64 sc1 loads) ------
// Lane's A-frag for slice ks = tile T(ks) = (ks*4 + (lane>>4))*64 + rbase +
// (lane&15), i.e. u64 offset T*2. Slice stride = 256 tiles = 512 u64.
__device__ __forceinline__ void ldb(u64 *dst, const u64 *ap, int ks) {
#pragma unroll
  for (int q = 0; q < 8; ++q) {
    dst[2 * q]     = ald64(ap + (size_t)(ks + q) * 512);
    dst[2 * q + 1] = ald64(ap + (size_t)(ks + q) * 512 + 1);
  }
}
__device__ __forceinline__ void useb(f32x4 *acc, const u64 *src, const short *wl,
                                     int nkoff, int ks, int lane) {
#pragma unroll
  for (int q = 0; q < 8; ++q) {
    union { u64 u[2]; bfrag v; } cc;
    cc.u[0] = src[2 * q]; cc.u[1] = src[2 * q + 1];
    const short *wp = wl + (((size_t)(nkoff + ks + q) * 2) * 64 + lane) * 8;
    acc[0] = __builtin_amdgcn_mfma_f32_16x16x32_bf16(cc.v, *(const bfrag *)wp, acc[0], 0, 0, 0);
    acc[1] = __builtin_amdgcn_mfma_f32_16x16x32_bf16(cc.v, *(const bfrag *)(wp + 512), acc[1], 0, 0, 0);
  }
}
__device__ void seg_h(f32x4 *acc, const unsigned short *hb, const short *wl,
                      int nkoff, int lane, int rbase) {
  const u64 *ap = (const u64 *)hb +
                  ((size_t)((lane >> 4) * 64 + rbase + (lane & 15)) * 2);
  u64 A[16], B[16];
  ldb(A, ap, 0);
  ldb(B, ap, 8);
  useb(acc, A, wl, nkoff, 0, lane);
  ldb(A, ap, 16);
  useb(acc, B, wl, nkoff, 8, lane);
  ldb(B, ap, 24);
  useb(acc, A, wl, nkoff, 16, lane);
  useb(acc, B, wl, nkoff, 24, lane);
}
// x segment: K=256, fp32 read-only input, plain cached loads (unchanged).
__device__ void seg_x(f32x4 *acc, const float *xt, const short *wl, int lane, int rbase) {
  const float4 *xp = (const float4 *)(xt + (size_t)(rbase + (lane & 15)) * Sc * Ic) + (lane >> 4) * 2;
  float4 xv[16];
#pragma unroll
  for (int q = 0; q < 8; ++q) {
    xv[2 * q]     = xp[(size_t)q * 8];
    xv[2 * q + 1] = xp[(size_t)q * 8 + 1];
  }
#pragma unroll
  for (int q = 0; q < 8; ++q) {
    bfrag av;
    const float *f0 = (const float *)&xv[2 * q];
    const float *f1 = (const float *)&xv[2 * q + 1];
#pragma unroll
    for (int e = 0; e < 4; ++e) {
      av[e]     = (short)f2b(f0[e]);
      av[4 + e] = (short)f2b(f1[e]);
    }
    const short *wp = wl + (((size_t)q * 2) * 64 + lane) * 8;
    acc[0] = __builtin_amdgcn_mfma_f32_16x16x32_bf16(av, *(const bfrag *)wp, acc[0], 0, 0, 0);
    acc[1] = __builtin_amdgcn_mfma_f32_16x16x32_bf16(av, *(const bfrag *)(wp + 512), acc[1], 0, 0, 0);
  }
}

// ---------------- epilogues (tiled addressing, sc1 word ops) -----------------
__device__ void store_sig(unsigned short *out, f32x4 *acc, int c0, int lane, int rbase) {
#pragma unroll
  for (int nt = 0; nt < 2; ++nt) {
    int col = c0 + nt * 16 + (lane & 15);
#pragma unroll
    for (int j = 0; j < 4; ++j) {
      float v = 1.f / (1.f + expf(-acc[nt][j]));
      float vo = __shfl_xor(v, 1);
      if (!(lane & 1)) {
        int row = rbase + (lane >> 4) * 4 + j;
        ast32((unsigned *)out + tidx32(row, col),
              (unsigned)f2b(v) | ((unsigned)f2b(vo) << 16));
      }
    }
  }
}
__device__ void store_rh(unsigned short *out, const unsigned short *hb, f32x4 *acc,
                         int c0, int lane, int rbase) {
  unsigned hw[8];
#pragma unroll
  for (int nt = 0; nt < 2; ++nt)
#pragma unroll
    for (int j = 0; j < 4; ++j)
      if (!(lane & 1)) {
        int col = c0 + nt * 16 + (lane & 15);
        int row = rbase + (lane >> 4) * 4 + j;
        hw[nt * 4 + j] = ald32((const unsigned *)hb + tidx32(row, col));
      }
#pragma unroll
  for (int nt = 0; nt < 2; ++nt) {
    int col = c0 + nt * 16 + (lane & 15);
#pragma unroll
    for (int j = 0; j < 4; ++j) {
      float v = 1.f / (1.f + expf(-acc[nt][j]));
      float vo = __shfl_xor(v, 1);
      if (!(lane & 1)) {
        unsigned w = hw[nt * 4 + j];
        int row = rbase + (lane >> 4) * 4 + j;
        unsigned pk = (unsigned)f2b(v * b2f((unsigned short)(w & 0xffff)))
                    | ((unsigned)f2b(vo * b2f((unsigned short)(w >> 16))) << 16);
        ast32((unsigned *)out + tidx32(row, col), pk);
      }
    }
  }
}
__device__ void store_gupd(unsigned short *hnew, const unsigned short *hold,
                           const unsigned short *zb, f32x4 *acc, int c0, int lane, int rbase) {
  unsigned zw[8], hw[8];
#pragma unroll
  for (int nt = 0; nt < 2; ++nt)
#pragma unroll
    for (int j = 0; j < 4; ++j)
      if (!(lane & 1)) {
        int col = c0 + nt * 16 + (lane & 15);
        size_t iw = tidx32(rbase + (lane >> 4) * 4 + j, col);
        zw[nt * 4 + j] = ald32((const unsigned *)zb + iw);
        hw[nt * 4 + j] = ald32((const unsigned *)hold + iw);
      }
#pragma unroll
  for (int nt = 0; nt < 2; ++nt) {
    int col = c0 + nt * 16 + (lane & 15);
#pragma unroll
    for (int j = 0; j < 4; ++j) {
      float g = tanhf(acc[nt][j]);
      float go = __shfl_xor(g, 1);
      if (!(lane & 1)) {
        unsigned wz = zw[nt * 4 + j], wh = hw[nt * 4 + j];
        float zl = b2f((unsigned short)(wz & 0xffff)), zh = b2f((unsigned short)(wz >> 16));
        float hl = b2f((unsigned short)(wh & 0xffff)), hh = b2f((unsigned short)(wh >> 16));
        float hn0 = zl * hl + (1.f - zl) * g;
        float hn1 = zh * hh + (1.f - zh) * go;
        ast32((unsigned *)hnew + tidx32(rbase + (lane >> 4) * 4 + j, col),
              (unsigned)f2b(hn0) | ((unsigned)f2b(hn1) << 16));
      }
    }
  }
}

// ---------------- weight packing (unchanged) ---------------------------------
__device__ void pack_weights(short *wl, const float *W1, int K1, int ld1,
                             const float *W2, int K2, int ld2, int c0) {
  int NK = (K1 + K2) / 32;
  for (int slot = threadIdx.x; slot < NK * 128; slot += TPB) {
    int ks = slot >> 7, rem = slot & 127, nt = rem >> 6, ln = rem & 63;
    int c = c0 + nt * 16 + (ln & 15);
    int k0 = ks * 32 + (ln >> 4) * 8;
    short *dst = wl + (((size_t)ks * 2 + nt) * 64 + ln) * 8;
#pragma unroll
    for (int j = 0; j < 8; ++j) {
      int k = k0 + j;
      float w = (k < K1) ? W1[(size_t)k * ld1 + c] : W2[(size_t)(k - K1) * ld2 + c];
      dst[j] = (short)f2b(w);
    }
  }
}

// ---------------- main --------------------------------------------------------
__global__ void __launch_bounds__(TPB) gru_df(Args a) {
  extern __shared__ short wl[];
  const int wg = blockIdx.x, tid = threadIdx.x;
  const int lane = tid & 63, wid = tid >> 6, rbase = wid * 16;
  const int gate = (wg < 32) ? 0 : (wg < 64) ? 1 : (wg < 96) ? 2 :
                   (wg < 128) ? 3 : (wg < 160) ? 4 : (wg < 192) ? 5 : 6;
  const int c0 = (gate == 6) ? (wg - 192) * 32 : (wg - gate * 32) * 32;
  static const int K1tab[7] = {256, 256, 256, 1024, 1024, 1024, 1024};
  static const int K2tab[7] = {1024, 1024, 1024, 1024, 1024, 1024, 0};
  const int ld1 = (gate == 6) ? Oc : Hc;

  pack_weights(wl, a.W1[gate], K1tab[gate], ld1, a.W2[gate], K2tab[gate], Hc, c0);

  // per-thread poll assignment: (slot, threshold offset); thr = t + off
  int pslot = -1, poff = 0;
  if (gate <= 1) {
    if (tid < 32) { pslot = 64 + tid; poff = 1; }                 // g0
  } else if (gate == 2) {
    if (tid < 64)       { pslot = tid;              poff = 2; }   // zr0
    else if (tid < 128) { pslot = 96 + (tid - 64);  poff = 0; }   // zr1 (WAR)
    else if (tid < 160) { pslot = 160 + (tid - 128); poff = 0; }  // g1 (WAR)
  } else if (gate <= 4) {
    if (tid < 32)      { pslot = 64 + tid;          poff = 2; }   // g0
    else if (tid < 64) { pslot = 160 + (tid - 32);  poff = 1; }   // g1
  } else if (gate == 5) {
    if (tid < 64)       { pslot = 96 + tid;         poff = 2; }   // zr1
    else if (tid < 96)  { pslot = 64 + (tid - 64);  poff = 2; }   // g0
    else if (tid < 104) { pslot = 192 + (tid - 96); poff = 0; }   // y (WAR)
  } else {
    if (tid < 32) { pslot = 160 + tid; poff = 2; }                // g1
  }

  // init h(-1) into buf1, TILED layout: u32 slot u -> tile=u>>2, word=u&3,
  // row=tile&63, oct=tile>>6, cols = oct*8 + word*2 + {0,1}
  for (int u = wg * TPB + tid; u < Bc * Hc / 2; u += NWG * TPB) {
    int tile = u >> 2, word = u & 3;
    int b = tile & 63, oct = tile >> 6;
    int c = oct * 8 + word * 2;
    const float *s0 = a.h0in + (size_t)(b * 2) * Hc + c;
    const float *s1 = a.h0in + (size_t)(b * 2 + 1) * Hc + c;
    ast32((unsigned *)a.h0[1] + u, (unsigned)f2b(s0[0]) | ((unsigned)f2b(s0[1]) << 16));
    ast32((unsigned *)a.h1[1] + u, (unsigned)f2b(s1[0]) | ((unsigned)f2b(s1[1]) << 16));
  }
  stamp(a.sl, wg, 1);
  waitslots(a.sl, (tid < NWG) ? tid : -1, 1);

  const float *bias = a.bias[gate];

  if (gate <= 1) {                                   // ---- zr0
    for (int t = 0; t < Sc; ++t) {
      waitslots(a.sl, pslot, (pslot >= 0) ? t + poff : 0);
      const unsigned short *h0c = a.h0[(t + 1) & 1];             // h0(t-1)
      float b0 = bias[c0 + (lane & 15)], b1 = bias[c0 + 16 + (lane & 15)];
      f32x4 acc[2] = {{b0, b0, b0, b0}, {b1, b1, b1, b1}};
      seg_x(acc, a.x + (size_t)t * Ic, wl, lane, rbase);
      seg_h(acc, h0c, wl, 8, lane, rbase);
      if (gate == 0) store_sig(a.z0[t & 1], acc, c0, lane, rbase);
      else           store_rh(a.rh0[t & 1], h0c, acc, c0, lane, rbase);
      stamp(a.sl, wg, t + 2);
    }
  } else if (gate == 2) {                            // ---- g0
    for (int t = 0; t < Sc; ++t) {
      waitslots(a.sl, pslot, (pslot >= 0) ? t + poff : 0);
      const unsigned short *h0c = a.h0[(t + 1) & 1];
      unsigned short *h0n = a.h0[t & 1];                          // h0(t)
      float b0 = bias[c0 + (lane & 15)], b1 = bias[c0 + 16 + (lane & 15)];
      f32x4 acc[2] = {{b0, b0, b0, b0}, {b1, b1, b1, b1}};
      seg_x(acc, a.x + (size_t)t * Ic, wl, lane, rbase);
      seg_h(acc, a.rh0[t & 1], wl, 8, lane, rbase);
      store_gupd(h0n, h0c, a.z0[t & 1], acc, c0, lane, rbase);
      stamp(a.sl, wg, t + 2);
    }
    // hs epilogue: final h0(1023), h1(1023) in buf1 (tiled -> row-major fp32)
    {
      int eslot = -1;
      if (tid < 32) eslot = 64 + tid;
      else if (tid < 64) eslot = 160 + (tid - 32);
      waitslots(a.sl, eslot, Sc + 1);
    }
    for (int k = (wg - 64) * TPB + tid; k < Bc * 2 * Hc; k += 32 * TPB) {
      int b = k >> 11, l = (k >> 10) & 1, h = k & 1023;
      const unsigned short *src = l ? a.h1[1] : a.h0[1];
      size_t i16 = ((size_t)(h >> 3) * 64 + b) * 8 + (h & 7);
      unsigned wv = ald32((const unsigned *)src + (i16 >> 1));
      a.hs[k] = b2f((unsigned short)((h & 1) ? (wv >> 16) : (wv & 0xffff)));
    }
  } else if (gate <= 4) {                            // ---- zr1
    for (int t = 0; t < Sc; ++t) {
      waitslots(a.sl, pslot, (pslot >= 0) ? t + poff : 0);
      const unsigned short *h0n = a.h0[t & 1];                    // h0(t)
      const unsigned short *h1c = a.h1[(t + 1) & 1];              // h1(t-1)
      float b0 = bias[c0 + (lane & 15)], b1 = bias[c0 + 16 + (lane & 15)];
      f32x4 acc[2] = {{b0, b0, b0, b0}, {b1, b1, b1, b1}};
      seg_h(acc, h0n, wl, 0, lane, rbase);
      seg_h(acc, h1c, wl, 32, lane, rbase);
      if (gate == 3) store_sig(a.z1[t & 1], acc, c0, lane, rbase);
      else           store_rh(a.rh1[t & 1], h1c, acc, c0, lane, rbase);
      stamp(a.sl, wg, t + 2);
    }
  } else if (gate == 5) {                            // ---- g1
    for (int t = 0; t < Sc; ++t) {
      waitslots(a.sl, pslot, (pslot >= 0) ? t + poff : 0);
      const unsigned short *h0n = a.h0[t & 1];
      const unsigned short *h1c = a.h1[(t + 1) & 1];
      unsigned short *h1n = a.h1[t & 1];                          // h1(t)
      float b0 = bias[c0 + (lane & 15)], b1 = bias[c0 + 16 + (lane & 15)];
      f32x4 acc[2] = {{b0, b0, b0, b0}, {b1, b1, b1, b1}};
      seg_h(acc, h0n, wl, 0, lane, rbase);
      seg_h(acc, a.rh1[t & 1], wl, 32, lane, rbase);
      store_gupd(h1n, h1c, a.z1[t & 1], acc, c0, lane, rbase);
      stamp(a.sl, wg, t + 2);
    }
  } else {                                           // ---- y
    for (int t = 0; t < Sc; ++t) {
      waitslots(a.sl, pslot, (pslot >= 0) ? t + poff : 0);
      const unsigned short *h1t = a.h1[t & 1];                    // h1(t)
      float b0 = bias[c0 + (lane & 15)], b1 = bias[c0 + 16 + (lane & 15)];
      f32x4 acc[2] = {{b0, b0, b0, b0}, {b1, b1, b1, b1}};
      seg_h(acc, h1t, wl, 0, lane, rbase);
#pragma unroll
      for (int nt = 0; nt < 2; ++nt) {
        int col = c0 + nt * 16 + (lane & 15);
#pragma unroll
        for (int j = 0; j < 4; ++j) {
          int row = rbase + (lane >> 4) * 4 + j;
          a.y[((size_t)row * Sc + t) * Oc + col] = acc[nt][j];
        }
      }
      stamp(a.sl, wg, t + 2);
    }
  }
}

extern "C" void kernel_launch(void *const *d_in, const int *in_sizes, int n_in,
                              void *d_out, int out_size, void *d_ws, size_t ws_size,
                              hipStream_t stream) {
  (void)in_sizes; (void)n_in; (void)out_size; (void)ws_size;
  Args a;
  a.x    = (const float *)d_in[0];
  a.h0in = (const float *)d_in[1];
  a.W1[0] = (const float *)d_in[2];  a.W2[0] = (const float *)d_in[5];  a.bias[0] = (const float *)d_in[6];
  a.W1[1] = (const float *)d_in[3];  a.W2[1] = (const float *)d_in[7];  a.bias[1] = (const float *)d_in[8];
  a.W1[2] = (const float *)d_in[4];  a.W2[2] = (const float *)d_in[9];  a.bias[2] = (const float *)d_in[10];
  a.W1[3] = (const float *)d_in[11]; a.W2[3] = (const float *)d_in[14]; a.bias[3] = (const float *)d_in[15];
  a.W1[4] = (const float *)d_in[12]; a.W2[4] = (const float *)d_in[16]; a.bias[4] = (const float *)d_in[17];
  a.W1[5] = (const float *)d_in[13]; a.W2[5] = (const float *)d_in[18]; a.bias[5] = (const float *)d_in[19];
  a.W1[6] = (const float *)d_in[20]; a.W2[6] = nullptr;                 a.bias[6] = (const float *)d_in[21];

  char *w = (char *)d_ws;
  a.h0[0]  = (unsigned short *)(w + 0);
  a.h0[1]  = (unsigned short *)(w + 131072);
  a.h1[0]  = (unsigned short *)(w + 262144);
  a.h1[1]  = (unsigned short *)(w + 393216);
  a.z0[0]  = (unsigned short *)(w + 524288);
  a.z0[1]  = (unsigned short *)(w + 655360);
  a.rh0[0] = (unsigned short *)(w + 786432);
  a.rh0[1] = (unsigned short *)(w + 917504);
  a.z1[0]  = (unsigned short *)(w + 1048576);
  a.z1[1]  = (unsigned short *)(w + 1179648);
  a.rh1[0] = (unsigned short *)(w + 1310720);
  a.rh1[1] = (unsigned short *)(w + 1441792);
  a.sl     = (unsigned *)(w + 1572864);
  a.y   = (float *)d_out;
  a.hs  = a.y + (size_t)Bc * Sc * Oc;

  (void)hipMemsetAsync(a.sl, 0, 32768, stream);
  (void)hipFuncSetAttribute((const void *)gru_df,
                            hipFuncAttributeMaxDynamicSharedMemorySize, 131072);
  gru_df<<<NWG, TPB, 131072, stream>>>(a);
}

// Round 16
// 37500.226 us; speedup vs baseline: 1.1177x; 1.0071x over previous
//
#include <hip/hip_runtime.h>
#include <hip/hip_bf16.h>
#include <stdint.h>

// ============================================================================
// 2-layer GRU — ROUND 16: ANTI-THROTTLE busy-poll (A/B vs R15).
//   B=64, S=1024, I=256, H=1024, O=256, L=2
// R8-R15 post-mortem: all sync/coherence/coalescing rewrites land in the
// 37-73ms band; VALUBusy ~2%. Hypothesis: power mgmt DOWNCLOCKS the ~98%-
// idle GPU (s_sleep-parked waves), inflating every latency by the clock
// ratio. This round: ONE change vs R15 — poll backoff s_sleep(2) -> 32-FMA
// dependent VALU burn (asm sink keeps it live). Clocks should pin at boost.
// Everything else (tiled state, coalesced sc1 loads, relaxed stamps,
// pipeline, numerics) byte-identical to R15.
//   zr0(t): g0 off1        g0(t): zr0 off2, zr1 off0, g1 off0
//   zr1(t): g0 off2, g1 off1    g1(t): zr1 off2, g0 off2, y off0
//   y(t):   g1 off2        hs:    g0,g1 >= Sc+1
// ============================================================================

#define NWG 200
#define TPB 256

typedef unsigned long long u64;
typedef __attribute__((ext_vector_type(8))) short bfrag;
typedef __attribute__((ext_vector_type(4))) float f32x4;

constexpr int Bc = 64, Sc = 1024, Ic = 256, Hc = 1024, Oc = 256;

struct Args {
  const float *x, *h0in;
  const float *W1[7], *W2[7], *bias[7];
  unsigned short *h0[2], *h1[2], *z0[2], *rh0[2], *z1[2], *rh1[2];
  unsigned *sl;       // 200 stamp slots, 128B apart
  float *y, *hs;
};

__device__ __forceinline__ u64 ald64(const void *p) {
  return __hip_atomic_load((const u64 *)p, __ATOMIC_RELAXED, __HIP_MEMORY_SCOPE_AGENT);
}
__device__ __forceinline__ unsigned ald32(const void *p) {
  return __hip_atomic_load((const unsigned *)p, __ATOMIC_RELAXED, __HIP_MEMORY_SCOPE_AGENT);
}
__device__ __forceinline__ void ast32(void *p, unsigned v) {
  __hip_atomic_store((unsigned *)p, v, __ATOMIC_RELAXED, __HIP_MEMORY_SCOPE_AGENT);
}
__device__ __forceinline__ unsigned short f2b(float x) {
  __hip_bfloat16 b = __float2bfloat16(x);
  return __builtin_bit_cast(unsigned short, b);
}
__device__ __forceinline__ float b2f(unsigned short u) {
  return __uint_as_float(((unsigned)u) << 16);
}
// tiled u32 index for (row, col): tile = (col>>3)*64+row, word = (col&7)>>1
__device__ __forceinline__ size_t tidx32(int row, int col) {
  return ((size_t)(col >> 3) * 64 + row) * 4 + ((col & 7) >> 1);
}

// ---------------- dataflow sync: busy-poll keeps clocks boosted -------------
__device__ void waitslots(const unsigned *sl, int pslot, int pthr) {
  __shared__ int notdone;
  float d = 1.0f;
  while (true) {
    int bad = 0;
    if (pslot >= 0)
      bad = ((int)ald32(sl + (size_t)pslot * 32) < pthr);
    if (threadIdx.x == 0) notdone = 0;
    __syncthreads();
    if (bad) notdone = 1;
    __syncthreads();
    if (!notdone) break;
    // ~128-cycle dependent VALU burn instead of s_sleep: keeps DPM at boost.
#pragma unroll
    for (int i = 0; i < 32; ++i) d = fmaf(d, 1.0000001f, 1e-30f);
    asm volatile("" :: "v"(d));   // keep chain live, no side effects
  }
}
__device__ void stamp(unsigned *sl, int wg, unsigned v) {
  __syncthreads();   // vmcnt drain: all sc1 stores ACKed at LLC before stamp
  if (threadIdx.x == 0)
    __hip_atomic_store(sl + (size_t)wg * 32, v, __ATOMIC_RELAXED, __HIP_MEMORY_SCOPE_AGENT);
}

// ---------------- MFMA segments (tiled state, coalesced u64 sc1 loads) ------
__device__ __forceinline__ void ldb(u64 *dst, const u64 *ap, int ks) {
#pragma unroll
  for (int q = 0; q < 8; ++q) {
    dst[2 * q]     = ald64(ap + (size_t)(ks + q) * 512);
    dst[2 * q + 1] = ald64(ap + (size_t)(ks + q) * 512 + 1);
  }
}
__device__ __forceinline__ void useb(f32x4 *acc, const u64 *src, const short *wl,
                                     int nkoff, int ks, int lane) {
#pragma unroll
  for (int q = 0; q < 8; ++q) {
    union { u64 u[2]; bfrag v; } cc;
    cc.u[0] = src[2 * q]; cc.u[1] = src[2 * q + 1];
    const short *wp = wl + (((size_t)(nkoff + ks + q) * 2) * 64 + lane) * 8;
    acc[0] = __builtin_amdgcn_mfma_f32_16x16x32_bf16(cc.v, *(const bfrag *)wp, acc[0], 0, 0, 0);
    acc[1] = __builtin_amdgcn_mfma_f32_16x16x32_bf16(cc.v, *(const bfrag *)(wp + 512), acc[1], 0, 0, 0);
  }
}
__device__ void seg_h(f32x4 *acc, const unsigned short *hb, const short *wl,
                      int nkoff, int lane, int rbase) {
  const u64 *ap = (const u64 *)hb +
                  ((size_t)((lane >> 4) * 64 + rbase + (lane & 15)) * 2);
  u64 A[16], B[16];
  ldb(A, ap, 0);
  ldb(B, ap, 8);
  useb(acc, A, wl, nkoff, 0, lane);
  ldb(A, ap, 16);
  useb(acc, B, wl, nkoff, 8, lane);
  ldb(B, ap, 24);
  useb(acc, A, wl, nkoff, 16, lane);
  useb(acc, B, wl, nkoff, 24, lane);
}
// x segment: K=256, fp32 read-only input, plain cached loads (unchanged).
__device__ void seg_x(f32x4 *acc, const float *xt, const short *wl, int lane, int rbase) {
  const float4 *xp = (const float4 *)(xt + (size_t)(rbase + (lane & 15)) * Sc * Ic) + (lane >> 4) * 2;
  float4 xv[16];
#pragma unroll
  for (int q = 0; q < 8; ++q) {
    xv[2 * q]     = xp[(size_t)q * 8];
    xv[2 * q + 1] = xp[(size_t)q * 8 + 1];
  }
#pragma unroll
  for (int q = 0; q < 8; ++q) {
    bfrag av;
    const float *f0 = (const float *)&xv[2 * q];
    const float *f1 = (const float *)&xv[2 * q + 1];
#pragma unroll
    for (int e = 0; e < 4; ++e) {
      av[e]     = (short)f2b(f0[e]);
      av[4 + e] = (short)f2b(f1[e]);
    }
    const short *wp = wl + (((size_t)q * 2) * 64 + lane) * 8;
    acc[0] = __builtin_amdgcn_mfma_f32_16x16x32_bf16(av, *(const bfrag *)wp, acc[0], 0, 0, 0);
    acc[1] = __builtin_amdgcn_mfma_f32_16x16x32_bf16(av, *(const bfrag *)(wp + 512), acc[1], 0, 0, 0);
  }
}

// ---------------- epilogues (tiled addressing, sc1 word ops) -----------------
__device__ void store_sig(unsigned short *out, f32x4 *acc, int c0, int lane, int rbase) {
#pragma unroll
  for (int nt = 0; nt < 2; ++nt) {
    int col = c0 + nt * 16 + (lane & 15);
#pragma unroll
    for (int j = 0; j < 4; ++j) {
      float v = 1.f / (1.f + expf(-acc[nt][j]));
      float vo = __shfl_xor(v, 1);
      if (!(lane & 1)) {
        int row = rbase + (lane >> 4) * 4 + j;
        ast32((unsigned *)out + tidx32(row, col),
              (unsigned)f2b(v) | ((unsigned)f2b(vo) << 16));
      }
    }
  }
}
__device__ void store_rh(unsigned short *out, const unsigned short *hb, f32x4 *acc,
                         int c0, int lane, int rbase) {
  unsigned hw[8];
#pragma unroll
  for (int nt = 0; nt < 2; ++nt)
#pragma unroll
    for (int j = 0; j < 4; ++j)
      if (!(lane & 1)) {
        int col = c0 + nt * 16 + (lane & 15);
        int row = rbase + (lane >> 4) * 4 + j;
        hw[nt * 4 + j] = ald32((const unsigned *)hb + tidx32(row, col));
      }
#pragma unroll
  for (int nt = 0; nt < 2; ++nt) {
    int col = c0 + nt * 16 + (lane & 15);
#pragma unroll
    for (int j = 0; j < 4; ++j) {
      float v = 1.f / (1.f + expf(-acc[nt][j]));
      float vo = __shfl_xor(v, 1);
      if (!(lane & 1)) {
        unsigned w = hw[nt * 4 + j];
        int row = rbase + (lane >> 4) * 4 + j;
        unsigned pk = (unsigned)f2b(v * b2f((unsigned short)(w & 0xffff)))
                    | ((unsigned)f2b(vo * b2f((unsigned short)(w >> 16))) << 16);
        ast32((unsigned *)out + tidx32(row, col), pk);
      }
    }
  }
}
__device__ void store_gupd(unsigned short *hnew, const unsigned short *hold,
                           const unsigned short *zb, f32x4 *acc, int c0, int lane, int rbase) {
  unsigned zw[8], hw[8];
#pragma unroll
  for (int nt = 0; nt < 2; ++nt)
#pragma unroll
    for (int j = 0; j < 4; ++j)
      if (!(lane & 1)) {
        int col = c0 + nt * 16 + (lane & 15);
        size_t iw = tidx32(rbase + (lane >> 4) * 4 + j, col);
        zw[nt * 4 + j] = ald32((const unsigned *)zb + iw);
        hw[nt * 4 + j] = ald32((const unsigned *)hold + iw);
      }
#pragma unroll
  for (int nt = 0; nt < 2; ++nt) {
    int col = c0 + nt * 16 + (lane & 15);
#pragma unroll
    for (int j = 0; j < 4; ++j) {
      float g = tanhf(acc[nt][j]);
      float go = __shfl_xor(g, 1);
      if (!(lane & 1)) {
        unsigned wz = zw[nt * 4 + j], wh = hw[nt * 4 + j];
        float zl = b2f((unsigned short)(wz & 0xffff)), zh = b2f((unsigned short)(wz >> 16));
        float hl = b2f((unsigned short)(wh & 0xffff)), hh = b2f((unsigned short)(wh >> 16));
        float hn0 = zl * hl + (1.f - zl) * g;
        float hn1 = zh * hh + (1.f - zh) * go;
        ast32((unsigned *)hnew + tidx32(rbase + (lane >> 4) * 4 + j, col),
              (unsigned)f2b(hn0) | ((unsigned)f2b(hn1) << 16));
      }
    }
  }
}

// ---------------- weight packing (unchanged) ---------------------------------
__device__ void pack_weights(short *wl, const float *W1, int K1, int ld1,
                             const float *W2, int K2, int ld2, int c0) {
  int NK = (K1 + K2) / 32;
  for (int slot = threadIdx.x; slot < NK * 128; slot += TPB) {
    int ks = slot >> 7, rem = slot & 127, nt = rem >> 6, ln = rem & 63;
    int c = c0 + nt * 16 + (ln & 15);
    int k0 = ks * 32 + (ln >> 4) * 8;
    short *dst = wl + (((size_t)ks * 2 + nt) * 64 + ln) * 8;
#pragma unroll
    for (int j = 0; j < 8; ++j) {
      int k = k0 + j;
      float w = (k < K1) ? W1[(size_t)k * ld1 + c] : W2[(size_t)(k - K1) * ld2 + c];
      dst[j] = (short)f2b(w);
    }
  }
}

// ---------------- main --------------------------------------------------------
__global__ void __launch_bounds__(TPB) gru_df(Args a) {
  extern __shared__ short wl[];
  const int wg = blockIdx.x, tid = threadIdx.x;
  const int lane = tid & 63, wid = tid >> 6, rbase = wid * 16;
  const int gate = (wg < 32) ? 0 : (wg < 64) ? 1 : (wg < 96) ? 2 :
                   (wg < 128) ? 3 : (wg < 160) ? 4 : (wg < 192) ? 5 : 6;
  const int c0 = (gate == 6) ? (wg - 192) * 32 : (wg - gate * 32) * 32;
  static const int K1tab[7] = {256, 256, 256, 1024, 1024, 1024, 1024};
  static const int K2tab[7] = {1024, 1024, 1024, 1024, 1024, 1024, 0};
  const int ld1 = (gate == 6) ? Oc : Hc;

  pack_weights(wl, a.W1[gate], K1tab[gate], ld1, a.W2[gate], K2tab[gate], Hc, c0);

  // per-thread poll assignment: (slot, threshold offset); thr = t + off
  int pslot = -1, poff = 0;
  if (gate <= 1) {
    if (tid < 32) { pslot = 64 + tid; poff = 1; }                 // g0
  } else if (gate == 2) {
    if (tid < 64)       { pslot = tid;              poff = 2; }   // zr0
    else if (tid < 128) { pslot = 96 + (tid - 64);  poff = 0; }   // zr1 (WAR)
    else if (tid < 160) { pslot = 160 + (tid - 128); poff = 0; }  // g1 (WAR)
  } else if (gate <= 4) {
    if (tid < 32)      { pslot = 64 + tid;          poff = 2; }   // g0
    else if (tid < 64) { pslot = 160 + (tid - 32);  poff = 1; }   // g1
  } else if (gate == 5) {
    if (tid < 64)       { pslot = 96 + tid;         poff = 2; }   // zr1
    else if (tid < 96)  { pslot = 64 + (tid - 64);  poff = 2; }   // g0
    else if (tid < 104) { pslot = 192 + (tid - 96); poff = 0; }   // y (WAR)
  } else {
    if (tid < 32) { pslot = 160 + tid; poff = 2; }                // g1
  }

  // init h(-1) into buf1, TILED layout
  for (int u = wg * TPB + tid; u < Bc * Hc / 2; u += NWG * TPB) {
    int tile = u >> 2, word = u & 3;
    int b = tile & 63, oct = tile >> 6;
    int c = oct * 8 + word * 2;
    const float *s0 = a.h0in + (size_t)(b * 2) * Hc + c;
    const float *s1 = a.h0in + (size_t)(b * 2 + 1) * Hc + c;
    ast32((unsigned *)a.h0[1] + u, (unsigned)f2b(s0[0]) | ((unsigned)f2b(s0[1]) << 16));
    ast32((unsigned *)a.h1[1] + u, (unsigned)f2b(s1[0]) | ((unsigned)f2b(s1[1]) << 16));
  }
  stamp(a.sl, wg, 1);
  waitslots(a.sl, (tid < NWG) ? tid : -1, 1);

  const float *bias = a.bias[gate];

  if (gate <= 1) {                                   // ---- zr0
    for (int t = 0; t < Sc; ++t) {
      waitslots(a.sl, pslot, (pslot >= 0) ? t + poff : 0);
      const unsigned short *h0c = a.h0[(t + 1) & 1];             // h0(t-1)
      float b0 = bias[c0 + (lane & 15)], b1 = bias[c0 + 16 + (lane & 15)];
      f32x4 acc[2] = {{b0, b0, b0, b0}, {b1, b1, b1, b1}};
      seg_x(acc, a.x + (size_t)t * Ic, wl, lane, rbase);
      seg_h(acc, h0c, wl, 8, lane, rbase);
      if (gate == 0) store_sig(a.z0[t & 1], acc, c0, lane, rbase);
      else           store_rh(a.rh0[t & 1], h0c, acc, c0, lane, rbase);
      stamp(a.sl, wg, t + 2);
    }
  } else if (gate == 2) {                            // ---- g0
    for (int t = 0; t < Sc; ++t) {
      waitslots(a.sl, pslot, (pslot >= 0) ? t + poff : 0);
      const unsigned short *h0c = a.h0[(t + 1) & 1];
      unsigned short *h0n = a.h0[t & 1];                          // h0(t)
      float b0 = bias[c0 + (lane & 15)], b1 = bias[c0 + 16 + (lane & 15)];
      f32x4 acc[2] = {{b0, b0, b0, b0}, {b1, b1, b1, b1}};
      seg_x(acc, a.x + (size_t)t * Ic, wl, lane, rbase);
      seg_h(acc, a.rh0[t & 1], wl, 8, lane, rbase);
      store_gupd(h0n, h0c, a.z0[t & 1], acc, c0, lane, rbase);
      stamp(a.sl, wg, t + 2);
    }
    // hs epilogue: final h0(1023), h1(1023) in buf1 (tiled -> row-major fp32)
    {
      int eslot = -1;
      if (tid < 32) eslot = 64 + tid;
      else if (tid < 64) eslot = 160 + (tid - 32);
      waitslots(a.sl, eslot, Sc + 1);
    }
    for (int k = (wg - 64) * TPB + tid; k < Bc * 2 * Hc; k += 32 * TPB) {
      int b = k >> 11, l = (k >> 10) & 1, h = k & 1023;
      const unsigned short *src = l ? a.h1[1] : a.h0[1];
      size_t i16 = ((size_t)(h >> 3) * 64 + b) * 8 + (h & 7);
      unsigned wv = ald32((const unsigned *)src + (i16 >> 1));
      a.hs[k] = b2f((unsigned short)((h & 1) ? (wv >> 16) : (wv & 0xffff)));
    }
  } else if (gate <= 4) {                            // ---- zr1
    for (int t = 0; t < Sc; ++t) {
      waitslots(a.sl, pslot, (pslot >= 0) ? t + poff : 0);
      const unsigned short *h0n = a.h0[t & 1];                    // h0(t)
      const unsigned short *h1c = a.h1[(t + 1) & 1];              // h1(t-1)
      float b0 = bias[c0 + (lane & 15)], b1 = bias[c0 + 16 + (lane & 15)];
      f32x4 acc[2] = {{b0, b0, b0, b0}, {b1, b1, b1, b1}};
      seg_h(acc, h0n, wl, 0, lane, rbase);
      seg_h(acc, h1c, wl, 32, lane, rbase);
      if (gate == 3) store_sig(a.z1[t & 1], acc, c0, lane, rbase);
      else           store_rh(a.rh1[t & 1], h1c, acc, c0, lane, rbase);
      stamp(a.sl, wg, t + 2);
    }
  } else if (gate == 5) {                            // ---- g1
    for (int t = 0; t < Sc; ++t) {
      waitslots(a.sl, pslot, (pslot >= 0) ? t + poff : 0);
      const unsigned short *h0n = a.h0[t & 1];
      const unsigned short *h1c = a.h1[(t + 1) & 1];
      unsigned short *h1n = a.h1[t & 1];                          // h1(t)
      float b0 = bias[c0 + (lane & 15)], b1 = bias[c0 + 16 + (lane & 15)];
      f32x4 acc[2] = {{b0, b0, b0, b0}, {b1, b1, b1, b1}};
      seg_h(acc, h0n, wl, 0, lane, rbase);
      seg_h(acc, a.rh1[t & 1], wl, 32, lane, rbase);
      store_gupd(h1n, h1c, a.z1[t & 1], acc, c0, lane, rbase);
      stamp(a.sl, wg, t + 2);
    }
  } else {                                           // ---- y
    for (int t = 0; t < Sc; ++t) {
      waitslots(a.sl, pslot, (pslot >= 0) ? t + poff : 0);
      const unsigned short *h1t = a.h1[t & 1];                    // h1(t)
      float b0 = bias[c0 + (lane & 15)], b1 = bias[c0 + 16 + (lane & 15)];
      f32x4 acc[2] = {{b0, b0, b0, b0}, {b1, b1, b1, b1}};
      seg_h(acc, h1t, wl, 0, lane, rbase);
#pragma unroll
      for (int nt = 0; nt < 2; ++nt) {
        int col = c0 + nt * 16 + (lane & 15);
#pragma unroll
        for (int j = 0; j < 4; ++j) {
          int row = rbase + (lane >> 4) * 4 + j;
          a.y[((size_t)row * Sc + t) * Oc + col] = acc[nt][j];
        }
      }
      stamp(a.sl, wg, t + 2);
    }
  }
}

extern "C" void kernel_launch(void *const *d_in, const int *in_sizes, int n_in,
                              void *d_out, int out_size, void *d_ws, size_t ws_size,
                              hipStream_t stream) {
  (void)in_sizes; (void)n_in; (void)out_size; (void)ws_size;
  Args a;
  a.x    = (const float *)d_in[0];
  a.h0in = (const float *)d_in[1];
  a.W1[0] = (const float *)d_in[2];  a.W2[0] = (const float *)d_in[5];  a.bias[0] = (const float *)d_in[6];
  a.W1[1] = (const float *)d_in[3];  a.W2[1] = (const float *)d_in[7];  a.bias[1] = (const float *)d_in[8];
  a.W1[2] = (const float *)d_in[4];  a.W2[2] = (const float *)d_in[9];  a.bias[2] = (const float *)d_in[10];
  a.W1[3] = (const float *)d_in[11]; a.W2[3] = (const float *)d_in[14]; a.bias[3] = (const float *)d_in[15];
  a.W1[4] = (const float *)d_in[12]; a.W2[4] = (const float *)d_in[16]; a.bias[4] = (const float *)d_in[17];
  a.W1[5] = (const float *)d_in[13]; a.W2[5] = (const float *)d_in[18]; a.bias[5] = (const float *)d_in[19];
  a.W1[6] = (const float *)d_in[20]; a.W2[6] = nullptr;                 a.bias[6] = (const float *)d_in[21];

  char *w = (char *)d_ws;
  a.h0[0]  = (unsigned short *)(w + 0);
  a.h0[1]  = (unsigned short *)(w + 131072);
  a.h1[0]  = (unsigned short *)(w + 262144);
  a.h1[1]  = (unsigned short *)(w + 393216);
  a.z0[0]  = (unsigned short *)(w + 524288);
  a.z0[1]  = (unsigned short *)(w + 655360);
  a.rh0[0] = (unsigned short *)(w + 786432);
  a.rh0[1] = (unsigned short *)(w + 917504);
  a.z1[0]  = (unsigned short *)(w + 1048576);
  a.z1[1]  = (unsigned short *)(w + 1179648);
  a.rh1[0] = (unsigned short *)(w + 1310720);
  a.rh1[1] = (unsigned short *)(w + 1441792);
  a.sl     = (unsigned *)(w + 1572864);
  a.y   = (float *)d_out;
  a.hs  = a.y + (size_t)Bc * Sc * Oc;

  (void)hipMemsetAsync(a.sl, 0, 32768, stream);
  (void)hipFuncSetAttribute((const void *)gru_df,
                            hipFuncAttributeMaxDynamicSharedMemorySize, 131072);
  gru_df<<<NWG, TPB, 131072, stream>>>(a);
}

// Round 17
// 33797.672 us; speedup vs baseline: 1.2402x; 1.1096x over previous
//
#include <hip/hip_runtime.h>
#include <hip/hip_bf16.h>
#include <stdint.h>

// ============================================================================
// 2-layer GRU — ROUND 17: batched asm sc1 loads (R14 retried, "=&v" fixed).
//   B=64, S=1024, I=256, H=1024, O=256, L=2
// Theory: __hip_atomic_load is handled conservatively (no clustering, per-
// load waitcnt) -> 64 serialized ~300ns LLC loads/gate ~= the invariant
// 15-18us/hop seen R8-R16. Fix: inline-asm global_load_dwordx4 sc1 batches
// of 8 with EARLY-CLOBBER outputs (R14 crashed for lack of "&": results
// clobbered later loads' address VGPRs), register-tied counted vmcnt waits.
// Epilogue z/h/rh reads batched the same way. Layout/sync/math = R15/R16.
//   zr0(t): g0 off1        g0(t): zr0 off2, zr1 off0, g1 off0
//   zr1(t): g0 off2, g1 off1    g1(t): zr1 off2, g0 off2, y off0
//   y(t):   g1 off2        hs:    g0,g1 >= Sc+1
// ============================================================================

#define NWG 200
#define TPB 256

typedef unsigned long long u64;
typedef __attribute__((ext_vector_type(8))) short bfrag;
typedef __attribute__((ext_vector_type(4))) float f32x4;

constexpr int Bc = 64, Sc = 1024, Ic = 256, Hc = 1024, Oc = 256;

struct Args {
  const float *x, *h0in;
  const float *W1[7], *W2[7], *bias[7];
  unsigned short *h0[2], *h1[2], *z0[2], *rh0[2], *z1[2], *rh1[2];
  unsigned *sl;
  float *y, *hs;
};

__device__ __forceinline__ unsigned ald32(const void *p) {
  return __hip_atomic_load((const unsigned *)p, __ATOMIC_RELAXED, __HIP_MEMORY_SCOPE_AGENT);
}
__device__ __forceinline__ void ast32(void *p, unsigned v) {
  __hip_atomic_store((unsigned *)p, v, __ATOMIC_RELAXED, __HIP_MEMORY_SCOPE_AGENT);
}
__device__ __forceinline__ unsigned short f2b(float x) {
  __hip_bfloat16 b = __float2bfloat16(x);
  return __builtin_bit_cast(unsigned short, b);
}
__device__ __forceinline__ float b2f(unsigned short u) {
  return __uint_as_float(((unsigned)u) << 16);
}
__device__ __forceinline__ size_t tidx32(int row, int col) {
  return ((size_t)(col >> 3) * 64 + row) * 4 + ((col & 7) >> 1);
}

// ---------------- dataflow sync (unchanged from R16) -------------------------
__device__ void waitslots(const unsigned *sl, int pslot, int pthr) {
  __shared__ int notdone;
  float d = 1.0f;
  while (true) {
    int bad = 0;
    if (pslot >= 0)
      bad = ((int)ald32(sl + (size_t)pslot * 32) < pthr);
    if (threadIdx.x == 0) notdone = 0;
    __syncthreads();
    if (bad) notdone = 1;
    __syncthreads();
    if (!notdone) break;
#pragma unroll
    for (int i = 0; i < 32; ++i) d = fmaf(d, 1.0000001f, 1e-30f);
    asm volatile("" :: "v"(d));
  }
}
__device__ void stamp(unsigned *sl, int wg, unsigned v) {
  __syncthreads();
  if (threadIdx.x == 0)
    __hip_atomic_store(sl + (size_t)wg * 32, v, __ATOMIC_RELAXED, __HIP_MEMORY_SCOPE_AGENT);
}

// ---------------- batched sc1 fragment loads (early-clobber!) ---------------
__device__ __forceinline__ void ld8(bfrag *F, const bfrag *tp) {
  asm volatile(
    "global_load_dwordx4 %0, %8, off sc1\n\t"
    "global_load_dwordx4 %1, %9, off sc1\n\t"
    "global_load_dwordx4 %2, %10, off sc1\n\t"
    "global_load_dwordx4 %3, %11, off sc1\n\t"
    "global_load_dwordx4 %4, %12, off sc1\n\t"
    "global_load_dwordx4 %5, %13, off sc1\n\t"
    "global_load_dwordx4 %6, %14, off sc1\n\t"
    "global_load_dwordx4 %7, %15, off sc1"
    : "=&v"(F[0]), "=&v"(F[1]), "=&v"(F[2]), "=&v"(F[3]),
      "=&v"(F[4]), "=&v"(F[5]), "=&v"(F[6]), "=&v"(F[7])
    : "v"(tp), "v"(tp + 256), "v"(tp + 512), "v"(tp + 768),
      "v"(tp + 1024), "v"(tp + 1280), "v"(tp + 1536), "v"(tp + 1792)
    : "memory");
}
__device__ __forceinline__ void waitvm8(bfrag *F) {
  asm volatile("s_waitcnt vmcnt(8)"
    : "+v"(F[0]), "+v"(F[1]), "+v"(F[2]), "+v"(F[3]),
      "+v"(F[4]), "+v"(F[5]), "+v"(F[6]), "+v"(F[7]) ::);
}
__device__ __forceinline__ void waitvm0(bfrag *F) {
  asm volatile("s_waitcnt vmcnt(0)"
    : "+v"(F[0]), "+v"(F[1]), "+v"(F[2]), "+v"(F[3]),
      "+v"(F[4]), "+v"(F[5]), "+v"(F[6]), "+v"(F[7]) ::);
}
// batched dword loads for epilogues
__device__ __forceinline__ void ld8d(unsigned *o, const unsigned *const p[8]) {
  asm volatile(
    "global_load_dword %0, %8, off sc1\n\t"
    "global_load_dword %1, %9, off sc1\n\t"
    "global_load_dword %2, %10, off sc1\n\t"
    "global_load_dword %3, %11, off sc1\n\t"
    "global_load_dword %4, %12, off sc1\n\t"
    "global_load_dword %5, %13, off sc1\n\t"
    "global_load_dword %6, %14, off sc1\n\t"
    "global_load_dword %7, %15, off sc1"
    : "=&v"(o[0]), "=&v"(o[1]), "=&v"(o[2]), "=&v"(o[3]),
      "=&v"(o[4]), "=&v"(o[5]), "=&v"(o[6]), "=&v"(o[7])
    : "v"(p[0]), "v"(p[1]), "v"(p[2]), "v"(p[3]),
      "v"(p[4]), "v"(p[5]), "v"(p[6]), "v"(p[7])
    : "memory");
}
__device__ __forceinline__ void wait8d(unsigned *o) {
  asm volatile("s_waitcnt vmcnt(0)"
    : "+v"(o[0]), "+v"(o[1]), "+v"(o[2]), "+v"(o[3]),
      "+v"(o[4]), "+v"(o[5]), "+v"(o[6]), "+v"(o[7]) ::);
}

// ---------------- MFMA segments ----------------------------------------------
__device__ __forceinline__ void use8(f32x4 *acc, const bfrag *F, const short *wl,
                                     int nkoff, int ks0, int lane) {
#pragma unroll
  for (int q = 0; q < 8; ++q) {
    const short *wp = wl + (((size_t)(nkoff + ks0 + q) * 2) * 64 + lane) * 8;
    acc[0] = __builtin_amdgcn_mfma_f32_16x16x32_bf16(F[q], *(const bfrag *)wp, acc[0], 0, 0, 0);
    acc[1] = __builtin_amdgcn_mfma_f32_16x16x32_bf16(F[q], *(const bfrag *)(wp + 512), acc[1], 0, 0, 0);
  }
}
__device__ void seg_h(f32x4 *acc, const unsigned short *hb, const short *wl,
                      int nkoff, int lane, int rbase) {
  const bfrag *tp = (const bfrag *)hb + ((lane >> 4) * 64 + rbase + (lane & 15));
  bfrag F0[8], F1[8];
  ld8(F0, tp);
  ld8(F1, tp + 2048);
  waitvm8(F0); use8(acc, F0, wl, nkoff, 0, lane);
  ld8(F0, tp + 4096);
  waitvm8(F1); use8(acc, F1, wl, nkoff, 8, lane);
  ld8(F1, tp + 6144);
  waitvm8(F0); use8(acc, F0, wl, nkoff, 16, lane);
  waitvm0(F1); use8(acc, F1, wl, nkoff, 24, lane);
}
__device__ void seg_x(f32x4 *acc, const float *xt, const short *wl, int lane, int rbase) {
  const float4 *xp = (const float4 *)(xt + (size_t)(rbase + (lane & 15)) * Sc * Ic) + (lane >> 4) * 2;
  float4 xv[16];
#pragma unroll
  for (int q = 0; q < 8; ++q) {
    xv[2 * q]     = xp[(size_t)q * 8];
    xv[2 * q + 1] = xp[(size_t)q * 8 + 1];
  }
#pragma unroll
  for (int q = 0; q < 8; ++q) {
    bfrag av;
    const float *f0 = (const float *)&xv[2 * q];
    const float *f1 = (const float *)&xv[2 * q + 1];
#pragma unroll
    for (int e = 0; e < 4; ++e) {
      av[e]     = (short)f2b(f0[e]);
      av[4 + e] = (short)f2b(f1[e]);
    }
    const short *wp = wl + (((size_t)q * 2) * 64 + lane) * 8;
    acc[0] = __builtin_amdgcn_mfma_f32_16x16x32_bf16(av, *(const bfrag *)wp, acc[0], 0, 0, 0);
    acc[1] = __builtin_amdgcn_mfma_f32_16x16x32_bf16(av, *(const bfrag *)(wp + 512), acc[1], 0, 0, 0);
  }
}

// ---------------- epilogues (batched asm loads, sc1 stores) ------------------
__device__ void store_sig(unsigned short *out, f32x4 *acc, int c0, int lane, int rbase) {
#pragma unroll
  for (int nt = 0; nt < 2; ++nt) {
    int col = c0 + nt * 16 + (lane & 15);
#pragma unroll
    for (int j = 0; j < 4; ++j) {
      float v = 1.f / (1.f + expf(-acc[nt][j]));
      float vo = __shfl_xor(v, 1);
      if (!(lane & 1)) {
        int row = rbase + (lane >> 4) * 4 + j;
        ast32((unsigned *)out + tidx32(row, col),
              (unsigned)f2b(v) | ((unsigned)f2b(vo) << 16));
      }
    }
  }
}
__device__ void store_rh(unsigned short *out, const unsigned short *hb, f32x4 *acc,
                         int c0, int lane, int rbase) {
  const unsigned *hp[8];
#pragma unroll
  for (int nt = 0; nt < 2; ++nt)
#pragma unroll
    for (int j = 0; j < 4; ++j) {
      int col = c0 + nt * 16 + (lane & 15);
      int row = rbase + (lane >> 4) * 4 + j;
      hp[nt * 4 + j] = (const unsigned *)hb + tidx32(row, col);
    }
  unsigned hw[8];
  ld8d(hw, hp);
  wait8d(hw);
#pragma unroll
  for (int nt = 0; nt < 2; ++nt) {
    int col = c0 + nt * 16 + (lane & 15);
#pragma unroll
    for (int j = 0; j < 4; ++j) {
      float v = 1.f / (1.f + expf(-acc[nt][j]));
      float vo = __shfl_xor(v, 1);
      if (!(lane & 1)) {
        unsigned w = hw[nt * 4 + j];
        int row = rbase + (lane >> 4) * 4 + j;
        unsigned pk = (unsigned)f2b(v * b2f((unsigned short)(w & 0xffff)))
                    | ((unsigned)f2b(vo * b2f((unsigned short)(w >> 16))) << 16);
        ast32((unsigned *)out + tidx32(row, col), pk);
      }
    }
  }
}
__device__ void store_gupd(unsigned short *hnew, const unsigned short *hold,
                           const unsigned short *zb, f32x4 *acc, int c0, int lane, int rbase) {
  const unsigned *zp[8], *hp[8];
#pragma unroll
  for (int nt = 0; nt < 2; ++nt)
#pragma unroll
    for (int j = 0; j < 4; ++j) {
      int col = c0 + nt * 16 + (lane & 15);
      size_t iw = tidx32(rbase + (lane >> 4) * 4 + j, col);
      zp[nt * 4 + j] = (const unsigned *)zb + iw;
      hp[nt * 4 + j] = (const unsigned *)hold + iw;
    }
  unsigned zw[8], hw[8];
  ld8d(zw, zp);
  ld8d(hw, hp);
  wait8d(zw);
  wait8d(hw);
#pragma unroll
  for (int nt = 0; nt < 2; ++nt) {
    int col = c0 + nt * 16 + (lane & 15);
#pragma unroll
    for (int j = 0; j < 4; ++j) {
      float g = tanhf(acc[nt][j]);
      float go = __shfl_xor(g, 1);
      if (!(lane & 1)) {
        unsigned wz = zw[nt * 4 + j], wh = hw[nt * 4 + j];
        float zl = b2f((unsigned short)(wz & 0xffff)), zh = b2f((unsigned short)(wz >> 16));
        float hl = b2f((unsigned short)(wh & 0xffff)), hh = b2f((unsigned short)(wh >> 16));
        float hn0 = zl * hl + (1.f - zl) * g;
        float hn1 = zh * hh + (1.f - zh) * go;
        ast32((unsigned *)hnew + tidx32(rbase + (lane >> 4) * 4 + j, col),
              (unsigned)f2b(hn0) | ((unsigned)f2b(hn1) << 16));
      }
    }
  }
}

// ---------------- weight packing (unchanged) ---------------------------------
__device__ void pack_weights(short *wl, const float *W1, int K1, int ld1,
                             const float *W2, int K2, int ld2, int c0) {
  int NK = (K1 + K2) / 32;
  for (int slot = threadIdx.x; slot < NK * 128; slot += TPB) {
    int ks = slot >> 7, rem = slot & 127, nt = rem >> 6, ln = rem & 63;
    int c = c0 + nt * 16 + (ln & 15);
    int k0 = ks * 32 + (ln >> 4) * 8;
    short *dst = wl + (((size_t)ks * 2 + nt) * 64 + ln) * 8;
#pragma unroll
    for (int j = 0; j < 8; ++j) {
      int k = k0 + j;
      float w = (k < K1) ? W1[(size_t)k * ld1 + c] : W2[(size_t)(k - K1) * ld2 + c];
      dst[j] = (short)f2b(w);
    }
  }
}

// ---------------- main --------------------------------------------------------
__global__ void __launch_bounds__(TPB) gru_df(Args a) {
  extern __shared__ short wl[];
  const int wg = blockIdx.x, tid = threadIdx.x;
  const int lane = tid & 63, wid = tid >> 6, rbase = wid * 16;
  const int gate = (wg < 32) ? 0 : (wg < 64) ? 1 : (wg < 96) ? 2 :
                   (wg < 128) ? 3 : (wg < 160) ? 4 : (wg < 192) ? 5 : 6;
  const int c0 = (gate == 6) ? (wg - 192) * 32 : (wg - gate * 32) * 32;
  static const int K1tab[7] = {256, 256, 256, 1024, 1024, 1024, 1024};
  static const int K2tab[7] = {1024, 1024, 1024, 1024, 1024, 1024, 0};
  const int ld1 = (gate == 6) ? Oc : Hc;

  pack_weights(wl, a.W1[gate], K1tab[gate], ld1, a.W2[gate], K2tab[gate], Hc, c0);

  int pslot = -1, poff = 0;
  if (gate <= 1) {
    if (tid < 32) { pslot = 64 + tid; poff = 1; }
  } else if (gate == 2) {
    if (tid < 64)       { pslot = tid;              poff = 2; }
    else if (tid < 128) { pslot = 96 + (tid - 64);  poff = 0; }
    else if (tid < 160) { pslot = 160 + (tid - 128); poff = 0; }
  } else if (gate <= 4) {
    if (tid < 32)      { pslot = 64 + tid;          poff = 2; }
    else if (tid < 64) { pslot = 160 + (tid - 32);  poff = 1; }
  } else if (gate == 5) {
    if (tid < 64)       { pslot = 96 + tid;         poff = 2; }
    else if (tid < 96)  { pslot = 64 + (tid - 64);  poff = 2; }
    else if (tid < 104) { pslot = 192 + (tid - 96); poff = 0; }
  } else {
    if (tid < 32) { pslot = 160 + tid; poff = 2; }
  }

  for (int u = wg * TPB + tid; u < Bc * Hc / 2; u += NWG * TPB) {
    int tile = u >> 2, word = u & 3;
    int b = tile & 63, oct = tile >> 6;
    int c = oct * 8 + word * 2;
    const float *s0 = a.h0in + (size_t)(b * 2) * Hc + c;
    const float *s1 = a.h0in + (size_t)(b * 2 + 1) * Hc + c;
    ast32((unsigned *)a.h0[1] + u, (unsigned)f2b(s0[0]) | ((unsigned)f2b(s0[1]) << 16));
    ast32((unsigned *)a.h1[1] + u, (unsigned)f2b(s1[0]) | ((unsigned)f2b(s1[1]) << 16));
  }
  stamp(a.sl, wg, 1);
  waitslots(a.sl, (tid < NWG) ? tid : -1, 1);

  const float *bias = a.bias[gate];

  if (gate <= 1) {                                   // ---- zr0
    for (int t = 0; t < Sc; ++t) {
      waitslots(a.sl, pslot, (pslot >= 0) ? t + poff : 0);
      const unsigned short *h0c = a.h0[(t + 1) & 1];
      float b0 = bias[c0 + (lane & 15)], b1 = bias[c0 + 16 + (lane & 15)];
      f32x4 acc[2] = {{b0, b0, b0, b0}, {b1, b1, b1, b1}};
      seg_x(acc, a.x + (size_t)t * Ic, wl, lane, rbase);
      seg_h(acc, h0c, wl, 8, lane, rbase);
      if (gate == 0) store_sig(a.z0[t & 1], acc, c0, lane, rbase);
      else           store_rh(a.rh0[t & 1], h0c, acc, c0, lane, rbase);
      stamp(a.sl, wg, t + 2);
    }
  } else if (gate == 2) {                            // ---- g0
    for (int t = 0; t < Sc; ++t) {
      waitslots(a.sl, pslot, (pslot >= 0) ? t + poff : 0);
      const unsigned short *h0c = a.h0[(t + 1) & 1];
      unsigned short *h0n = a.h0[t & 1];
      float b0 = bias[c0 + (lane & 15)], b1 = bias[c0 + 16 + (lane & 15)];
      f32x4 acc[2] = {{b0, b0, b0, b0}, {b1, b1, b1, b1}};
      seg_x(acc, a.x + (size_t)t * Ic, wl, lane, rbase);
      seg_h(acc, a.rh0[t & 1], wl, 8, lane, rbase);
      store_gupd(h0n, h0c, a.z0[t & 1], acc, c0, lane, rbase);
      stamp(a.sl, wg, t + 2);
    }
    {
      int eslot = -1;
      if (tid < 32) eslot = 64 + tid;
      else if (tid < 64) eslot = 160 + (tid - 32);
      waitslots(a.sl, eslot, Sc + 1);
    }
    for (int k = (wg - 64) * TPB + tid; k < Bc * 2 * Hc; k += 32 * TPB) {
      int b = k >> 11, l = (k >> 10) & 1, h = k & 1023;
      const unsigned short *src = l ? a.h1[1] : a.h0[1];
      size_t i16 = ((size_t)(h >> 3) * 64 + b) * 8 + (h & 7);
      unsigned wv = ald32((const unsigned *)src + (i16 >> 1));
      a.hs[k] = b2f((unsigned short)((h & 1) ? (wv >> 16) : (wv & 0xffff)));
    }
  } else if (gate <= 4) {                            // ---- zr1
    for (int t = 0; t < Sc; ++t) {
      waitslots(a.sl, pslot, (pslot >= 0) ? t + poff : 0);
      const unsigned short *h0n = a.h0[t & 1];
      const unsigned short *h1c = a.h1[(t + 1) & 1];
      float b0 = bias[c0 + (lane & 15)], b1 = bias[c0 + 16 + (lane & 15)];
      f32x4 acc[2] = {{b0, b0, b0, b0}, {b1, b1, b1, b1}};
      seg_h(acc, h0n, wl, 0, lane, rbase);
      seg_h(acc, h1c, wl, 32, lane, rbase);
      if (gate == 3) store_sig(a.z1[t & 1], acc, c0, lane, rbase);
      else           store_rh(a.rh1[t & 1], h1c, acc, c0, lane, rbase);
      stamp(a.sl, wg, t + 2);
    }
  } else if (gate == 5) {                            // ---- g1
    for (int t = 0; t < Sc; ++t) {
      waitslots(a.sl, pslot, (pslot >= 0) ? t + poff : 0);
      const unsigned short *h0n = a.h0[t & 1];
      const unsigned short *h1c = a.h1[(t + 1) & 1];
      unsigned short *h1n = a.h1[t & 1];
      float b0 = bias[c0 + (lane & 15)], b1 = bias[c0 + 16 + (lane & 15)];
      f32x4 acc[2] = {{b0, b0, b0, b0}, {b1, b1, b1, b1}};
      seg_h(acc, h0n, wl, 0, lane, rbase);
      seg_h(acc, a.rh1[t & 1], wl, 32, lane, rbase);
      store_gupd(h1n, h1c, a.z1[t & 1], acc, c0, lane, rbase);
      stamp(a.sl, wg, t + 2);
    }
  } else {                                           // ---- y
    for (int t = 0; t < Sc; ++t) {
      waitslots(a.sl, pslot, (pslot >= 0) ? t + poff : 0);
      const unsigned short *h1t = a.h1[t & 1];
      float b0 = bias[c0 + (lane & 15)], b1 = bias[c0 + 16 + (lane & 15)];
      f32x4 acc[2] = {{b0, b0, b0, b0}, {b1, b1, b1, b1}};
      seg_h(acc, h1t, wl, 0, lane, rbase);
#pragma unroll
      for (int nt = 0; nt < 2; ++nt) {
        int col = c0 + nt * 16 + (lane & 15);
#pragma unroll
        for (int j = 0; j < 4; ++j) {
          int row = rbase + (lane >> 4) * 4 + j;
          a.y[((size_t)row * Sc + t) * Oc + col] = acc[nt][j];
        }
      }
      stamp(a.sl, wg, t + 2);
    }
  }
}

extern "C" void kernel_launch(void *const *d_in, const int *in_sizes, int n_in,
                              void *d_out, int out_size, void *d_ws, size_t ws_size,
                              hipStream_t stream) {
  (void)in_sizes; (void)n_in; (void)out_size; (void)ws_size;
  Args a;
  a.x    = (const float *)d_in[0];
  a.h0in = (const float *)d_in[1];
  a.W1[0] = (const float *)d_in[2];  a.W2[0] = (const float *)d_in[5];  a.bias[0] = (const float *)d_in[6];
  a.W1[1] = (const float *)d_in[3];  a.W2[1] = (const float *)d_in[7];  a.bias[1] = (const float *)d_in[8];
  a.W1[2] = (const float *)d_in[4];  a.W2[2] = (const float *)d_in[9];  a.bias[2] = (const float *)d_in[10];
  a.W1[3] = (const float *)d_in[11]; a.W2[3] = (const float *)d_in[14]; a.bias[3] = (const float *)d_in[15];
  a.W1[4] = (const float *)d_in[12]; a.W2[4] = (const float *)d_in[16]; a.bias[4] = (const float *)d_in[17];
  a.W1[5] = (const float *)d_in[13]; a.W2[5] = (const float *)d_in[18]; a.bias[5] = (const float *)d_in[19];
  a.W1[6] = (const float *)d_in[20]; a.W2[6] = nullptr;                 a.bias[6] = (const float *)d_in[21];

  char *w = (char *)d_ws;
  a.h0[0]  = (unsigned short *)(w + 0);
  a.h0[1]  = (unsigned short *)(w + 131072);
  a.h1[0]  = (unsigned short *)(w + 262144);
  a.h1[1]  = (unsigned short *)(w + 393216);
  a.z0[0]  = (unsigned short *)(w + 524288);
  a.z0[1]  = (unsigned short *)(w + 655360);
  a.rh0[0] = (unsigned short *)(w + 786432);
  a.rh0[1] = (unsigned short *)(w + 917504);
  a.z1[0]  = (unsigned short *)(w + 1048576);
  a.z1[1]  = (unsigned short *)(w + 1179648);
  a.rh1[0] = (unsigned short *)(w + 1310720);
  a.rh1[1] = (unsigned short *)(w + 1441792);
  a.sl     = (unsigned *)(w + 1572864);
  a.y   = (float *)d_out;
  a.hs  = a.y + (size_t)Bc * Sc * Oc;

  (void)hipMemsetAsync(a.sl, 0, 32768, stream);
  (void)hipFuncSetAttribute((const void *)gru_df,
                            hipFuncAttributeMaxDynamicSharedMemorySize, 131072);
  gru_df<<<NWG, TPB, 131072, stream>>>(a);
}